// Round 2
// baseline (225.594 us; speedup 1.0000x reference)
//
#include <hip/hip_runtime.h>

// Panorama: warp frame (4,1080,1920) via homography onto canvas (4,2048,3072),
// alpha-over composite. float32.
//
// R1: prepass interleaves frame planes -> RGBA float4 in d_ws so each bilinear
// tap is ONE 16B load; main kernel does 4 px/thread with float4 canvas/out.

#define FH 1080
#define FW 1920
#define CHh 2048
#define CWw 3072
#define FHW (FH * FW)
#define CHW (CHh * CWw)

__global__ __launch_bounds__(256) void interleave_kernel(
    const float* __restrict__ frame, float4* __restrict__ fi)
{
    const int idx = blockIdx.x * 256 + threadIdx.x;   // FHW == 8100*256
    float4 v;
    v.x = frame[idx];
    v.y = frame[FHW + idx];
    v.z = frame[2 * FHW + idx];
    v.w = frame[3 * FHW + idx];
    fi[idx] = v;
}

__global__ __launch_bounds__(256) void pano4_kernel(
    const float4* __restrict__ fi,
    const float* __restrict__ Hm,
    const float* __restrict__ canvas,
    float* __restrict__ out)
{
    const int t = blockIdx.x * 256 + threadIdx.x;   // CW/4 == 768 per row
    const int y = blockIdx.y;
    const int x4 = t * 4;
    const int q = y * (CWw / 4) + t;                // float4 index in a plane

    const float a  = Hm[0], b  = Hm[1], c  = Hm[2];
    const float d  = Hm[3], e  = Hm[4], f  = Hm[5];
    const float g  = Hm[6], hh = Hm[7], i9 = Hm[8];
    // adjugate (1/det cancels in perspective divide)
    const float A0 = e * i9 - f * hh, A1 = c * hh - b * i9, A2 = b * f - c * e;
    const float B0 = f * g  - d * i9, B1 = a * i9 - c * g,  B2 = c * d - a * f;
    const float C0 = d * hh - e * g,  C1 = b * g  - a * hh, C2 = a * e - b * d;

    const float4* cv = (const float4*)canvas;
    const float4 cr = cv[0 * (CHW / 4) + q];
    const float4 cg = cv[1 * (CHW / 4) + q];
    const float4 cb = cv[2 * (CHW / 4) + q];
    const float4 ca = cv[3 * (CHW / 4) + q];

    float wr[4], wg[4], wb[4], wa[4];
    const float yf = (float)y;

    #pragma unroll
    for (int p = 0; p < 4; ++p) {
        wr[p] = wg[p] = wb[p] = wa[p] = 0.f;
        const float xf = (float)(x4 + p);
        const float u = fmaf(A0, xf, fmaf(A1, yf, A2));
        const float v = fmaf(B0, xf, fmaf(B1, yf, B2));
        const float w = fmaf(C0, xf, fmaf(C1, yf, C2));
        const float invw = __builtin_amdgcn_rcpf(w);
        const float sx = u * invw;
        const float sy = v * invw;
        const float x0f = floorf(sx);
        const float y0f = floorf(sy);
        const float wx = sx - x0f;
        const float wy = sy - y0f;
        const int x0 = (int)x0f;
        const int y0 = (int)y0f;

        if (x0 >= -1 && x0 <= FW - 1 && y0 >= -1 && y0 <= FH - 1) {
            const int x1 = x0 + 1, y1 = y0 + 1;
            const float mx0 = (x0 >= 0) ? 1.f : 0.f;          // x0 <= FW-1 given
            const float mx1 = (x1 <= FW - 1) ? 1.f : 0.f;     // x1 >= 0 given
            const float my0 = (y0 >= 0) ? 1.f : 0.f;
            const float my1 = (y1 <= FH - 1) ? 1.f : 0.f;
            const int xc0 = min(max(x0, 0), FW - 1);
            const int xc1 = min(max(x1, 0), FW - 1);
            const int yc0 = min(max(y0, 0), FH - 1);
            const int yc1 = min(max(y1, 0), FH - 1);

            const float w00 = (1.f - wx) * (1.f - wy) * mx0 * my0;
            const float w01 = wx * (1.f - wy) * mx1 * my0;
            const float w10 = (1.f - wx) * wy * mx0 * my1;
            const float w11 = wx * wy * mx1 * my1;

            const float4 v00 = fi[yc0 * FW + xc0];
            const float4 v01 = fi[yc0 * FW + xc1];
            const float4 v10 = fi[yc1 * FW + xc0];
            const float4 v11 = fi[yc1 * FW + xc1];

            wr[p] = fmaf(w00, v00.x, fmaf(w01, v01.x, fmaf(w10, v10.x, w11 * v11.x)));
            wg[p] = fmaf(w00, v00.y, fmaf(w01, v01.y, fmaf(w10, v10.y, w11 * v11.y)));
            wb[p] = fmaf(w00, v00.z, fmaf(w01, v01.z, fmaf(w10, v10.z, w11 * v11.z)));
            wa[p] = fmaf(w00, v00.w, fmaf(w01, v01.w, fmaf(w10, v10.w, w11 * v11.w)));
        }
    }

    const float crr[4] = {cr.x, cr.y, cr.z, cr.w};
    const float cgg[4] = {cg.x, cg.y, cg.z, cg.w};
    const float cbb[4] = {cb.x, cb.y, cb.z, cb.w};
    const float caa[4] = {ca.x, ca.y, ca.z, ca.w};

    float orv[4], ogv[4], obv[4], oav[4];
    #pragma unroll
    for (int p = 0; p < 4; ++p) {
        const float k = caa[p] * (1.f - wa[p]);
        orv[p] = fmaf(wr[p], wa[p], crr[p] * k);
        ogv[p] = fmaf(wg[p], wa[p], cgg[p] * k);
        obv[p] = fmaf(wb[p], wa[p], cbb[p] * k);
        oav[p] = wa[p] + k;
    }

    float4* ov = (float4*)out;
    ov[0 * (CHW / 4) + q] = make_float4(orv[0], orv[1], orv[2], orv[3]);
    ov[1 * (CHW / 4) + q] = make_float4(ogv[0], ogv[1], ogv[2], ogv[3]);
    ov[2 * (CHW / 4) + q] = make_float4(obv[0], obv[1], obv[2], obv[3]);
    ov[3 * (CHW / 4) + q] = make_float4(oav[0], oav[1], oav[2], oav[3]);
}

// ---- fallback (R0 kernel) if d_ws is too small for the interleaved frame ----
__global__ __launch_bounds__(256) void pano_kernel(
    const float* __restrict__ frame,
    const float* __restrict__ Hm,
    const float* __restrict__ canvas,
    float* __restrict__ out)
{
    const int x = blockIdx.x * 256 + threadIdx.x;
    const int y = blockIdx.y;
    const int pix = y * CWw + x;

    const float a  = Hm[0], b  = Hm[1], c  = Hm[2];
    const float d  = Hm[3], e  = Hm[4], f  = Hm[5];
    const float g  = Hm[6], hh = Hm[7], i9 = Hm[8];
    const float A0 = e * i9 - f * hh, A1 = c * hh - b * i9, A2 = b * f - c * e;
    const float B0 = f * g  - d * i9, B1 = a * i9 - c * g,  B2 = c * d - a * f;
    const float C0 = d * hh - e * g,  C1 = b * g  - a * hh, C2 = a * e - b * d;

    const float xf = (float)x, yf = (float)y;
    const float u = A0 * xf + A1 * yf + A2;
    const float v = B0 * xf + B1 * yf + B2;
    const float w = C0 * xf + C1 * yf + C2;
    const float sx = u / w;
    const float sy = v / w;

    const float x0f = floorf(sx);
    const float y0f = floorf(sy);
    const float wx = sx - x0f;
    const float wy = sy - y0f;
    const int x0 = (int)x0f;
    const int y0 = (int)y0f;

    const float c0 = canvas[0 * CHW + pix];
    const float c1 = canvas[1 * CHW + pix];
    const float c2 = canvas[2 * CHW + pix];
    const float ac = canvas[3 * CHW + pix];

    float w0 = 0.f, w1 = 0.f, w2 = 0.f, as = 0.f;
    if (x0 >= -1 && x0 <= FW - 1 && y0 >= -1 && y0 <= FH - 1) {
        const int x1 = x0 + 1, y1 = y0 + 1;
        const float mx0 = (x0 >= 0) ? 1.f : 0.f;
        const float mx1 = (x1 <= FW - 1) ? 1.f : 0.f;
        const float my0 = (y0 >= 0) ? 1.f : 0.f;
        const float my1 = (y1 <= FH - 1) ? 1.f : 0.f;
        const int xc0 = min(max(x0, 0), FW - 1);
        const int xc1 = min(max(x1, 0), FW - 1);
        const int yc0 = min(max(y0, 0), FH - 1);
        const int yc1 = min(max(y1, 0), FH - 1);

        const float w00 = (1.f - wx) * (1.f - wy) * mx0 * my0;
        const float w01 = wx * (1.f - wy) * mx1 * my0;
        const float w10 = (1.f - wx) * wy * mx0 * my1;
        const float w11 = wx * wy * mx1 * my1;

        const int i00 = yc0 * FW + xc0;
        const int i01 = yc0 * FW + xc1;
        const int i10 = yc1 * FW + xc0;
        const int i11 = yc1 * FW + xc1;

        #pragma unroll
        for (int chn = 0; chn < 4; ++chn) {
            const float* fp = frame + chn * FHW;
            const float val = w00 * fp[i00] + w01 * fp[i01]
                            + w10 * fp[i10] + w11 * fp[i11];
            if (chn == 0) w0 = val;
            else if (chn == 1) w1 = val;
            else if (chn == 2) w2 = val;
            else as = val;
        }
    }

    const float k = ac * (1.f - as);
    out[0 * CHW + pix] = w0 * as + c0 * k;
    out[1 * CHW + pix] = w1 * as + c1 * k;
    out[2 * CHW + pix] = w2 * as + c2 * k;
    out[3 * CHW + pix] = as + k;
}

extern "C" void kernel_launch(void* const* d_in, const int* in_sizes, int n_in,
                              void* d_out, int out_size, void* d_ws, size_t ws_size,
                              hipStream_t stream) {
    const float* frame  = (const float*)d_in[0];
    const float* Hm     = (const float*)d_in[1];
    const float* canvas = (const float*)d_in[2];
    float* out = (float*)d_out;

    const size_t need = (size_t)FHW * sizeof(float4);   // 33,177,600 B
    if (ws_size >= need) {
        float4* fi = (float4*)d_ws;
        interleave_kernel<<<dim3(FHW / 256), dim3(256), 0, stream>>>(frame, fi);
        pano4_kernel<<<dim3(CWw / 4 / 256, CHh), dim3(256), 0, stream>>>(fi, Hm, canvas, out);
    } else {
        pano_kernel<<<dim3(CWw / 256, CHh), dim3(256), 0, stream>>>(frame, Hm, canvas, out);
    }
}

// Round 3
// 207.143 us; speedup vs baseline: 1.0891x; 1.0891x over previous
//
#include <hip/hip_runtime.h>

// Panorama: warp frame (4,1080,1920) via homography onto canvas (4,2048,3072),
// alpha-over composite. float32.
//
// R2: interleaved RGBA frame in d_ws (prepass), main kernel 1 px/thread so
// adjacent lanes gather adjacent frame pixels -> each bilinear tap is ONE
// coalesced float4 load (16B/lane, ~16 lines/wave). R1's 4px/thread made taps
// fully uncoalesced (64 lines/wave) — reverted.

#define FH 1080
#define FW 1920
#define CHh 2048
#define CWw 3072
#define FHW (FH * FW)
#define CHW (CHh * CWw)

__global__ __launch_bounds__(256) void interleave_kernel(
    const float* __restrict__ frame, float4* __restrict__ fi)
{
    const int idx = blockIdx.x * 256 + threadIdx.x;   // FHW == 8100*256
    float4 v;
    v.x = frame[idx];
    v.y = frame[FHW + idx];
    v.z = frame[2 * FHW + idx];
    v.w = frame[3 * FHW + idx];
    fi[idx] = v;
}

__global__ __launch_bounds__(256) void pano1_kernel(
    const float4* __restrict__ fi,
    const float* __restrict__ Hm,
    const float* __restrict__ canvas,
    float* __restrict__ out)
{
    const int x = blockIdx.x * 256 + threadIdx.x;   // CWw == 12*256
    const int y = blockIdx.y;
    const int pix = y * CWw + x;

    const float a  = Hm[0], b  = Hm[1], c  = Hm[2];
    const float d  = Hm[3], e  = Hm[4], f  = Hm[5];
    const float g  = Hm[6], hh = Hm[7], i9 = Hm[8];
    // adjugate (1/det cancels in perspective divide)
    const float A0 = e * i9 - f * hh, A1 = c * hh - b * i9, A2 = b * f - c * e;
    const float B0 = f * g  - d * i9, B1 = a * i9 - c * g,  B2 = c * d - a * f;
    const float C0 = d * hh - e * g,  C1 = b * g  - a * hh, C2 = a * e - b * d;

    const float xf = (float)x, yf = (float)y;
    const float u = fmaf(A0, xf, fmaf(A1, yf, A2));
    const float v = fmaf(B0, xf, fmaf(B1, yf, B2));
    const float w = fmaf(C0, xf, fmaf(C1, yf, C2));
    const float invw = __builtin_amdgcn_rcpf(w);
    const float sx = u * invw;
    const float sy = v * invw;

    const float x0f = floorf(sx);
    const float y0f = floorf(sy);
    const float wx = sx - x0f;
    const float wy = sy - y0f;
    const int x0 = (int)x0f;
    const int y0 = (int)y0f;

    // canvas loads issue early; independent of the gather chain
    const float c0 = canvas[0 * CHW + pix];
    const float c1 = canvas[1 * CHW + pix];
    const float c2 = canvas[2 * CHW + pix];
    const float ac = canvas[3 * CHW + pix];

    float wr = 0.f, wg = 0.f, wb = 0.f, wa = 0.f;

    if (x0 >= -1 && x0 <= FW - 1 && y0 >= -1 && y0 <= FH - 1) {
        const int x1 = x0 + 1, y1 = y0 + 1;
        const float mx0 = (x0 >= 0) ? 1.f : 0.f;        // x0 <= FW-1 given
        const float mx1 = (x1 <= FW - 1) ? 1.f : 0.f;   // x1 >= 0  given
        const float my0 = (y0 >= 0) ? 1.f : 0.f;
        const float my1 = (y1 <= FH - 1) ? 1.f : 0.f;
        const int xc0 = min(max(x0, 0), FW - 1);
        const int xc1 = min(max(x1, 0), FW - 1);
        const int yc0 = min(max(y0, 0), FH - 1);
        const int yc1 = min(max(y1, 0), FH - 1);

        const float w00 = (1.f - wx) * (1.f - wy) * mx0 * my0;
        const float w01 = wx * (1.f - wy) * mx1 * my0;
        const float w10 = (1.f - wx) * wy * mx0 * my1;
        const float w11 = wx * wy * mx1 * my1;

        const float4 v00 = fi[yc0 * FW + xc0];
        const float4 v01 = fi[yc0 * FW + xc1];
        const float4 v10 = fi[yc1 * FW + xc0];
        const float4 v11 = fi[yc1 * FW + xc1];

        wr = fmaf(w00, v00.x, fmaf(w01, v01.x, fmaf(w10, v10.x, w11 * v11.x)));
        wg = fmaf(w00, v00.y, fmaf(w01, v01.y, fmaf(w10, v10.y, w11 * v11.y)));
        wb = fmaf(w00, v00.z, fmaf(w01, v01.z, fmaf(w10, v10.z, w11 * v11.z)));
        wa = fmaf(w00, v00.w, fmaf(w01, v01.w, fmaf(w10, v10.w, w11 * v11.w)));
    }

    const float k = ac * (1.f - wa);
    out[0 * CHW + pix] = fmaf(wr, wa, c0 * k);
    out[1 * CHW + pix] = fmaf(wg, wa, c1 * k);
    out[2 * CHW + pix] = fmaf(wb, wa, c2 * k);
    out[3 * CHW + pix] = wa + k;
}

// ---- fallback (planar, no ws) ----
__global__ __launch_bounds__(256) void pano_kernel(
    const float* __restrict__ frame,
    const float* __restrict__ Hm,
    const float* __restrict__ canvas,
    float* __restrict__ out)
{
    const int x = blockIdx.x * 256 + threadIdx.x;
    const int y = blockIdx.y;
    const int pix = y * CWw + x;

    const float a  = Hm[0], b  = Hm[1], c  = Hm[2];
    const float d  = Hm[3], e  = Hm[4], f  = Hm[5];
    const float g  = Hm[6], hh = Hm[7], i9 = Hm[8];
    const float A0 = e * i9 - f * hh, A1 = c * hh - b * i9, A2 = b * f - c * e;
    const float B0 = f * g  - d * i9, B1 = a * i9 - c * g,  B2 = c * d - a * f;
    const float C0 = d * hh - e * g,  C1 = b * g  - a * hh, C2 = a * e - b * d;

    const float xf = (float)x, yf = (float)y;
    const float u = A0 * xf + A1 * yf + A2;
    const float v = B0 * xf + B1 * yf + B2;
    const float w = C0 * xf + C1 * yf + C2;
    const float sx = u / w;
    const float sy = v / w;

    const float x0f = floorf(sx);
    const float y0f = floorf(sy);
    const float wx = sx - x0f;
    const float wy = sy - y0f;
    const int x0 = (int)x0f;
    const int y0 = (int)y0f;

    const float c0 = canvas[0 * CHW + pix];
    const float c1 = canvas[1 * CHW + pix];
    const float c2 = canvas[2 * CHW + pix];
    const float ac = canvas[3 * CHW + pix];

    float w0 = 0.f, w1 = 0.f, w2 = 0.f, as = 0.f;
    if (x0 >= -1 && x0 <= FW - 1 && y0 >= -1 && y0 <= FH - 1) {
        const int x1 = x0 + 1, y1 = y0 + 1;
        const float mx0 = (x0 >= 0) ? 1.f : 0.f;
        const float mx1 = (x1 <= FW - 1) ? 1.f : 0.f;
        const float my0 = (y0 >= 0) ? 1.f : 0.f;
        const float my1 = (y1 <= FH - 1) ? 1.f : 0.f;
        const int xc0 = min(max(x0, 0), FW - 1);
        const int xc1 = min(max(x1, 0), FW - 1);
        const int yc0 = min(max(y0, 0), FH - 1);
        const int yc1 = min(max(y1, 0), FH - 1);

        const float w00 = (1.f - wx) * (1.f - wy) * mx0 * my0;
        const float w01 = wx * (1.f - wy) * mx1 * my0;
        const float w10 = (1.f - wx) * wy * mx0 * my1;
        const float w11 = wx * wy * mx1 * my1;

        const int i00 = yc0 * FW + xc0;
        const int i01 = yc0 * FW + xc1;
        const int i10 = yc1 * FW + xc0;
        const int i11 = yc1 * FW + xc1;

        #pragma unroll
        for (int chn = 0; chn < 4; ++chn) {
            const float* fp = frame + chn * FHW;
            const float val = w00 * fp[i00] + w01 * fp[i01]
                            + w10 * fp[i10] + w11 * fp[i11];
            if (chn == 0) w0 = val;
            else if (chn == 1) w1 = val;
            else if (chn == 2) w2 = val;
            else as = val;
        }
    }

    const float k = ac * (1.f - as);
    out[0 * CHW + pix] = w0 * as + c0 * k;
    out[1 * CHW + pix] = w1 * as + c1 * k;
    out[2 * CHW + pix] = w2 * as + c2 * k;
    out[3 * CHW + pix] = as + k;
}

extern "C" void kernel_launch(void* const* d_in, const int* in_sizes, int n_in,
                              void* d_out, int out_size, void* d_ws, size_t ws_size,
                              hipStream_t stream) {
    const float* frame  = (const float*)d_in[0];
    const float* Hm     = (const float*)d_in[1];
    const float* canvas = (const float*)d_in[2];
    float* out = (float*)d_out;

    const size_t need = (size_t)FHW * sizeof(float4);   // 33,177,600 B
    if (ws_size >= need) {
        float4* fi = (float4*)d_ws;
        interleave_kernel<<<dim3(FHW / 256), dim3(256), 0, stream>>>(frame, fi);
        pano1_kernel<<<dim3(CWw / 256, CHh), dim3(256), 0, stream>>>(fi, Hm, canvas, out);
    } else {
        pano_kernel<<<dim3(CWw / 256, CHh), dim3(256), 0, stream>>>(frame, Hm, canvas, out);
    }
}